// Round 7
// baseline (1161.005 us; speedup 1.0000x reference)
//
#include <hip/hip_runtime.h>

#define H 128
#define KV 256

typedef short bf16x8 __attribute__((ext_vector_type(8)));
typedef float f32x4 __attribute__((ext_vector_type(4)));
union FragU { uint4 u; bf16x8 s; };

__device__ __forceinline__ float bf2f(unsigned short u) {
  return __uint_as_float(((unsigned)u) << 16);
}
__device__ __forceinline__ unsigned short f2bf(float f) {
  unsigned b = __float_as_uint(f);
  b += 0x7FFFu + ((b >> 16) & 1u);   // round-to-nearest-even
  return (unsigned short)(b >> 16);
}

// node-array storage: fp32 (KB=false) or bf16 (KB=true) tier
template<bool KB>
__device__ __forceinline__ float nld(const void* a, size_t idx) {
  if (KB) return bf2f(((const unsigned short*)a)[idx]);
  else    return ((const float*)a)[idx];
}
template<bool KB>
__device__ __forceinline__ void nst(void* a, size_t idx, float v) {
  if (KB) ((unsigned short*)a)[idx] = f2bf(v);
  else    ((float*)a)[idx] = v;
}

__global__ __launch_bounds__(256) void k_zero(float* __restrict__ p, int n) {
  int i = blockIdx.x * 256 + threadIdx.x;
  if (i < n) p[i] = 0.f;
}

__global__ __launch_bounds__(256) void k_sentinel(float* __restrict__ out, int n) {
  int i = blockIdx.x * 256 + threadIdx.x;
  if (i < n) out[i] = 1000.0f;
}

// pack Wc1 (128x512 fp32) into bf16 B-fragment order for mfma 16x16x32
__global__ __launch_bounds__(256) void k_prep_w1(const float* __restrict__ Wc1,
                                                 uint4* __restrict__ w1f) {
  int t = blockIdx.x*256 + threadIdx.x;    // 8192 total
  int g = t >> 6, lane = t & 63;
  int q = g >> 5, kk = (g >> 3) & 3, ni = g & 7;
  int o = q*128 + ni*16 + (lane & 15);
  int kbase = kk*32 + (lane >> 4)*8;
  unsigned s[8];
  #pragma unroll
  for (int j = 0; j < 8; ++j) s[j] = f2bf(Wc1[(kbase+j)*512 + o]);
  uint4 u;
  u.x = s[0] | (s[1]<<16); u.y = s[2] | (s[3]<<16);
  u.z = s[4] | (s[5]<<16); u.w = s[6] | (s[7]<<16);
  w1f[g*64 + lane] = u;
}

// ---------- counting sort of edges by row ----------
__global__ __launch_bounds__(256) void k_hist(const int* __restrict__ row,
                                              int* __restrict__ counts, int E) {
  int e = blockIdx.x*256 + threadIdx.x;
  if (e < E) atomicAdd(&counts[row[e]], 1);
}

// single-block exclusive scan (wave-scan + cross-wave), also inits cursor
__global__ __launch_bounds__(1024) void k_scan(const int* __restrict__ counts,
                                               int* __restrict__ row_start,
                                               int* __restrict__ cursor, int n) {
  __shared__ int wsum[16];
  __shared__ int carry_s;
  const int tid = threadIdx.x, lane = tid & 63, wid = tid >> 6;
  if (tid == 0) carry_s = 0;
  __syncthreads();
  for (int base = 0; base < n; base += 1024) {
    int i = base + tid;
    int v = (i < n) ? counts[i] : 0;
    int s = v;
    #pragma unroll
    for (int off = 1; off < 64; off <<= 1) {
      int t = __shfl_up(s, off, 64);
      if (lane >= off) s += t;
    }
    if (lane == 63) wsum[wid] = s;
    __syncthreads();
    if (wid == 0 && lane < 16) {
      int w = wsum[lane];
      #pragma unroll
      for (int off = 1; off < 16; off <<= 1) {
        int t = __shfl_up(w, off, 16);
        if (lane >= off) w += t;
      }
      wsum[lane] = w;
    }
    __syncthreads();
    int wexcl = (wid == 0) ? 0 : wsum[wid-1];
    int excl = carry_s + wexcl + (s - v);
    if (i < n) { row_start[i] = excl; cursor[i] = excl; }
    __syncthreads();
    if (tid == 0) carry_s += wsum[15];
    __syncthreads();
  }
  if (threadIdx.x == 0) row_start[n] = carry_s;
}

__global__ __launch_bounds__(256) void k_scatter(const int* __restrict__ row,
                                                 int* __restrict__ cursor,
                                                 int* __restrict__ eidx, int E) {
  int e = blockIdx.x*256 + threadIdx.x;
  if (e < E) {
    int pos = atomicAdd(&cursor[row[e]], 1);
    eidx[pos] = e;
  }
}

// ---------- K1: qn = h@Wq+bq, kn/vn = deinterleaved h@Wkv[9:]+bkv ----------
template<bool KB>
__global__ __launch_bounds__(384) void k_node_proj(
    const float* __restrict__ h, const float* __restrict__ Wq,
    const float* __restrict__ bq, const float* __restrict__ Wkv,
    const float* __restrict__ bkv, void* __restrict__ qn,
    void* __restrict__ kn, void* __restrict__ vn, int N)
{
  __shared__ float hs[4][H];
  const int n0 = blockIdx.x * 4;
  const int t = threadIdx.x;
  for (int idx = t; idx < 4*H; idx += 384) {
    int nn = idx >> 7, jj = idx & 127;
    hs[nn][jj] = (n0 + nn < N) ? h[(size_t)(n0+nn)*H + jj] : 0.f;
  }
  __syncthreads();
  float a0 = 0.f, a1 = 0.f, a2 = 0.f, a3 = 0.f;
  if (t < H) {
    #pragma unroll 4
    for (int j = 0; j < H; ++j) {
      float w = Wq[j*H + t];
      a0 += hs[0][j]*w; a1 += hs[1][j]*w; a2 += hs[2][j]*w; a3 += hs[3][j]*w;
    }
    float b = bq[t];
    if (n0+0 < N) nst<KB>(qn, (size_t)(n0+0)*H + t, a0 + b);
    if (n0+1 < N) nst<KB>(qn, (size_t)(n0+1)*H + t, a1 + b);
    if (n0+2 < N) nst<KB>(qn, (size_t)(n0+2)*H + t, a2 + b);
    if (n0+3 < N) nst<KB>(qn, (size_t)(n0+3)*H + t, a3 + b);
  } else {
    int c = t - H;                 // column of 2H kv output
    #pragma unroll 4
    for (int j = 0; j < H; ++j) {
      float w = Wkv[(9 + j)*KV + c];
      a0 += hs[0][j]*w; a1 += hs[1][j]*w; a2 += hs[2][j]*w; a3 += hs[3][j]*w;
    }
    float b = bkv[c];
    void* dst = (c & 1) ? vn : kn;
    size_t ch = (size_t)(c >> 1);
    if (n0+0 < N) nst<KB>(dst, (size_t)(n0+0)*H + ch, a0 + b);
    if (n0+1 < N) nst<KB>(dst, (size_t)(n0+1)*H + ch, a1 + b);
    if (n0+2 < N) nst<KB>(dst, (size_t)(n0+2)*H + ch, a2 + b);
    if (n0+3 < N) nst<KB>(dst, (size_t)(n0+3)*H + ch, a3 + b);
  }
}

// ---------- K2: raw alpha per edge (CSR order for qn L1 reuse) ----------
template<bool KB>
__global__ __launch_bounds__(256) void k_edge_alpha(
    const float* __restrict__ coord, const int* __restrict__ row,
    const int* __restrict__ col, const float* __restrict__ Wkv,
    const int* __restrict__ eidx, const void* __restrict__ qn,
    const void* __restrict__ kn, float* __restrict__ aout, int E)
{
  __shared__ float wke[9*128];     // Wkv even cols (k weights for radial)
  const int tid = threadIdx.x;
  for (int idx = tid; idx < 9*128; idx += 256) {
    int p = idx >> 7, j = idx & 127;
    wke[idx] = Wkv[p*KV + 2*j];
  }
  __syncthreads();
  int lane = tid & 63;
  int gw = (blockIdx.x * 256 + tid) >> 6;
  int nw = (gridDim.x * 256) >> 6;
  int chunk = (E + nw - 1) / nw;
  int j0 = gw*chunk, j1 = min(E, j0 + chunk);
  for (int j = j0; j < j1; ++j) {
    int e = eidx[j];               // sorted by row -> qn[r] reused ~deg times
    int r = row[e], c = col[e];
    float cd[9], rad[9];
    #pragma unroll
    for (int i = 0; i < 9; ++i) cd[i] = coord[(size_t)r*9+i] - coord[(size_t)c*9+i];
    #pragma unroll
    for (int a = 0; a < 3; ++a)
      #pragma unroll
      for (int b = 0; b < 3; ++b)
        rad[a*3+b] = cd[a*3]*cd[b*3] + cd[a*3+1]*cd[b*3+1] + cd[a*3+2]*cd[b*3+2];
    float q0 = nld<KB>(qn, (size_t)r*H + lane);
    float q1 = nld<KB>(qn, (size_t)r*H + 64 + lane);
    float k0 = nld<KB>(kn, (size_t)c*H + lane);
    float k1 = nld<KB>(kn, (size_t)c*H + 64 + lane);
    #pragma unroll
    for (int p = 0; p < 9; ++p) {
      k0 += rad[p]*wke[p*128 + lane];
      k1 += rad[p]*wke[p*128 + 64 + lane];
    }
    float acc = q0*k0 + q1*k1;
    #pragma unroll
    for (int m = 32; m > 0; m >>= 1) acc += __shfl_xor(acc, m, 64);
    if (lane == 0) aout[e] = acc;
  }
}

// ---------- K3: per-row softmax normalize (CSR, no atomics) ----------
__global__ __launch_bounds__(256) void k_row_softmax(
    const int* __restrict__ row_start, const int* __restrict__ eidx,
    float* __restrict__ aout, int N)
{
  int r = blockIdx.x*256 + threadIdx.x;
  if (r >= N) return;
  int js = row_start[r], je = row_start[r+1];
  if (js >= je) return;
  float m = -1e30f;
  for (int j = js; j < je; ++j) m = fmaxf(m, aout[eidx[j]]);
  float s = 0.f;
  for (int j = js; j < je; ++j) s += __expf(aout[eidx[j]] - m);
  float inv = 1.f / s;              // s >= 1 (max edge contributes exp(0)=1)
  for (int j = js; j < je; ++j) {
    int ie = eidx[j];
    aout[ie] = __expf(aout[ie] - m) * inv;
  }
}

// ---------- K4: MFMA MLP per 128-edge tile -> mlpout[e][3] (no atomics) ----
#define EST 22   // einfo stride: cd[0..8] rad[9..17] c[18] cv[19..21]
template<bool KB>
__global__ __launch_bounds__(256) void k_edge_mlp(
    const float* __restrict__ coord, const int* __restrict__ row,
    const int* __restrict__ col, const float* __restrict__ Wkv,
    const float* __restrict__ Wc2, const void* __restrict__ vn,
    const uint4* __restrict__ w1f, float* __restrict__ mlpout, int E)
{
  __shared__ unsigned vt[128*64];     // 32KB: V tile bf16x2, 16B-chunk XOR swizzle
  __shared__ float einfo[128*EST];
  __shared__ float wvo[9*128];        // Wkv odd cols
  __shared__ float wc2s[512*3];
  const int tid = threadIdx.x;
  const int wid = tid >> 6, lane = tid & 63;
  const int quad = lane >> 4, colc = lane & 15;

  for (int idx = tid; idx < 9*128; idx += 256) {
    int p = idx >> 7, j = idx & 127;
    wvo[idx] = Wkv[p*KV + 2*j + 1];
  }
  for (int idx = tid; idx < 512*3; idx += 256) wc2s[idx] = Wc2[idx];

  // ---- phase 1: edge info ----
  const int e0 = blockIdx.x * 128;
  if (tid < 128) {
    int e = e0 + tid;
    float* ei = &einfo[tid*EST];
    if (e < E) {
      int r = row[e], c = col[e];
      float cd[9];
      #pragma unroll
      for (int i = 0; i < 9; ++i) cd[i] = coord[(size_t)r*9+i] - coord[(size_t)c*9+i];
      #pragma unroll
      for (int i = 0; i < 9; ++i) ei[i] = cd[i];
      #pragma unroll
      for (int a = 0; a < 3; ++a)
        #pragma unroll
        for (int b = 0; b < 3; ++b)
          ei[9 + a*3+b] = cd[a*3]*cd[b*3] + cd[a*3+1]*cd[b*3+1] + cd[a*3+2]*cd[b*3+2];
      ei[18] = __int_as_float(c);
    } else {
      #pragma unroll
      for (int i = 0; i < 19; ++i) ei[i] = 0.f;   // rad=0, c=0 -> inert
    }
  }
  __syncthreads();

  // ---- phase 2: V tile (each wave one edge per iteration) ----
  for (int i = 0; i < 32; ++i) {
    int el = i*4 + wid;
    const float* ei = &einfo[el*EST];
    float rad[9];
    #pragma unroll
    for (int p = 0; p < 9; ++p) rad[p] = ei[9+p];
    int c = __float_as_int(ei[18]);
    float v0 = nld<KB>(vn, (size_t)c*H + 2*lane);
    float v1 = nld<KB>(vn, (size_t)c*H + 2*lane + 1);
    #pragma unroll
    for (int p = 0; p < 9; ++p) {
      v0 += rad[p]*wvo[p*128 + 2*lane];
      v1 += rad[p]*wvo[p*128 + 2*lane + 1];
    }
    unsigned pk = (unsigned)f2bf(v0) | ((unsigned)f2bf(v1) << 16);
    vt[el*64 + (((lane>>2) ^ (el&15))<<2) + (lane&3)] = pk;
  }
  __syncthreads();

  // ---- phase 3: MFMA GEMM per o-quarter; accumulate cv in LDS ----
  const int mrow = wid*32;
  for (int q = 0; q < 4; ++q) {
    f32x4 acc[2][8];
    #pragma unroll
    for (int a = 0; a < 2; ++a)
      #pragma unroll
      for (int n = 0; n < 8; ++n) acc[a][n] = (f32x4){0.f,0.f,0.f,0.f};
    #pragma unroll
    for (int kk = 0; kk < 4; ++kk) {
      FragU bfr[8];
      #pragma unroll
      for (int n = 0; n < 8; ++n)
        bfr[n].u = w1f[(((q*4+kk)*8+n)<<6) + lane];
      FragU afr[2];
      #pragma unroll
      for (int a = 0; a < 2; ++a) {
        int rrow = mrow + a*16 + colc;
        int chunk = kk*4 + quad;
        afr[a].u = *((const uint4*)&vt[rrow*64 + ((chunk ^ (rrow&15))<<2)]);
      }
      #pragma unroll
      for (int a = 0; a < 2; ++a)
        #pragma unroll
        for (int n = 0; n < 8; ++n)
          acc[a][n] = __builtin_amdgcn_mfma_f32_16x16x32_bf16(
              afr[a].s, bfr[n].s, acc[a][n], 0, 0, 0);
    }
    float wch[8][3];
    #pragma unroll
    for (int n = 0; n < 8; ++n) {
      int o = q*128 + n*16 + colc;
      wch[n][0] = wc2s[o*3+0]; wch[n][1] = wc2s[o*3+1]; wch[n][2] = wc2s[o*3+2];
    }
    float part[2][4][3];
    #pragma unroll
    for (int a=0;a<2;++a)
      #pragma unroll
      for (int g=0;g<4;++g) { part[a][g][0]=0.f; part[a][g][1]=0.f; part[a][g][2]=0.f; }
    #pragma unroll
    for (int a = 0; a < 2; ++a)
      #pragma unroll
      for (int n = 0; n < 8; ++n)
        #pragma unroll
        for (int g = 0; g < 4; ++g) {
          float s = acc[a][n][g];
          float hs = s / (1.f + __expf(-s));   // silu
          part[a][g][0] += hs*wch[n][0];
          part[a][g][1] += hs*wch[n][1];
          part[a][g][2] += hs*wch[n][2];
        }
    #pragma unroll
    for (int off = 1; off < 16; off <<= 1)
      #pragma unroll
      for (int a=0;a<2;++a)
        #pragma unroll
        for (int g=0;g<4;++g) {
          part[a][g][0] += __shfl_xor(part[a][g][0], off, 64);
          part[a][g][1] += __shfl_xor(part[a][g][1], off, 64);
          part[a][g][2] += __shfl_xor(part[a][g][2], off, 64);
        }
    if (colc < 3) {
      int ch = colc;
      #pragma unroll
      for (int a = 0; a < 2; ++a)
        #pragma unroll
        for (int g = 0; g < 4; ++g) {
          int el = mrow + a*16 + quad*4 + g;    // C-layout row; unique (lane,el,ch)
          float* slot = &einfo[el*EST + 19 + ch];
          *slot = (q == 0) ? part[a][g][ch] : (*slot + part[a][g][ch]);
        }
    }
  }
  __syncthreads();
  // coalesced write-out of mlpout (128 edges x 3 ch)
  for (int idx = tid; idx < 128*3; idx += 256) {
    int el = idx / 3, ch = idx - el*3;
    int e = e0 + el;
    if (e < E) mlpout[(size_t)e*3 + ch] = einfo[el*EST + 19 + ch];
  }
}

// ---------- K5: per-row h_out AND coord_out (CSR, atomic-free) ----------
template<bool KB>
__global__ __launch_bounds__(256) void k_row_final(
    const float* __restrict__ h, const float* __restrict__ coord,
    const int* __restrict__ col, const float* __restrict__ Wkv,
    const int* __restrict__ row_start, const int* __restrict__ eidx,
    const float* __restrict__ aout, const void* __restrict__ vn,
    const float* __restrict__ mlpout, float* __restrict__ hout,
    float* __restrict__ cout, int N)
{
  __shared__ float wvo[9*128];     // Wkv odd cols (v weights for radial)
  const int tid = threadIdx.x;
  for (int idx = tid; idx < 9*128; idx += 256) {
    int p = idx >> 7, j = idx & 127;
    wvo[idx] = Wkv[p*KV + 2*j + 1];
  }
  __syncthreads();
  const int wid = tid >> 6, lane = tid & 63;
  const int r = blockIdx.x*4 + wid;
  if (r >= N) return;
  int js = row_start[r], je = row_start[r+1];
  float cr[9];
  #pragma unroll
  for (int i = 0; i < 9; ++i) cr[i] = coord[(size_t)r*9 + i];
  float acc0 = 0.f, acc1 = 0.f;
  float t[9], cg[9];
  #pragma unroll
  for (int p = 0; p < 9; ++p) { t[p] = 0.f; cg[p] = 0.f; }
  for (int j = js; j < je; ++j) {
    int ie = eidx[j];
    float a = aout[ie];
    int c = col[ie];
    float cd[9], rad[9];
    #pragma unroll
    for (int i = 0; i < 9; ++i) cd[i] = cr[i] - coord[(size_t)c*9+i];
    #pragma unroll
    for (int aa = 0; aa < 3; ++aa)
      #pragma unroll
      for (int bb = 0; bb < 3; ++bb)
        rad[aa*3+bb] = cd[aa*3]*cd[bb*3] + cd[aa*3+1]*cd[bb*3+1] + cd[aa*3+2]*cd[bb*3+2];
    acc0 += a * nld<KB>(vn, (size_t)c*H + 2*lane);
    acc1 += a * nld<KB>(vn, (size_t)c*H + 2*lane + 1);
    #pragma unroll
    for (int p = 0; p < 9; ++p) t[p] += a * rad[p];
    float cv0 = a * mlpout[(size_t)ie*3 + 0];
    float cv1 = a * mlpout[(size_t)ie*3 + 1];
    float cv2 = a * mlpout[(size_t)ie*3 + 2];
    #pragma unroll
    for (int d = 0; d < 3; ++d) {
      cg[0+d] += cv0 * cd[0+d];
      cg[3+d] += cv1 * cd[3+d];
      cg[6+d] += cv2 * cd[6+d];
    }
  }
  #pragma unroll
  for (int p = 0; p < 9; ++p) {
    acc0 += t[p] * wvo[p*128 + 2*lane];
    acc1 += t[p] * wvo[p*128 + 2*lane + 1];
  }
  hout[(size_t)r*H + 2*lane]     = h[(size_t)r*H + 2*lane]     + acc0;
  hout[(size_t)r*H + 2*lane + 1] = h[(size_t)r*H + 2*lane + 1] + acc1;
  if (lane == 0) {
    #pragma unroll
    for (int i = 0; i < 9; ++i) {
      float x = fminf(10.f, fmaxf(-10.f, cg[i]));
      cout[(size_t)r*9 + i] = cr[i] + x;
    }
  }
}

template<bool KB>
static void run_pipeline(const float* h, const float* coord,
                         const int* row, const int* col,
                         const float* Wq, const float* bq,
                         const float* Wkv, const float* bkv,
                         const float* Wc1, const float* Wc2,
                         void* d_ws, float* out, int N, int E,
                         hipStream_t stream)
{
  const size_t es = KB ? 2 : 4;
  char* p = (char*)d_ws;
  void* kn = p;                    p += (size_t)N*H*es;
  void* vn = p;                    p += (size_t)N*H*es;
  void* qn = p;                    p += (size_t)N*H*es;   // dead after alpha
  int* counts = (int*)p;           p += (size_t)N*4;
  int* row_start = (int*)p;        p += (size_t)(N+1)*4;
  int* cursor = (int*)p;           p += (size_t)N*4;
  int* eidx = (int*)p;             p += (size_t)E*4;
  uint4* w1f = (uint4*)((((size_t)p) + 15) & ~(size_t)15);
  // mlpout aliases qn (dead after k_edge_alpha); fits: 3*Epad*4 <= N*H*es
  float* mlpout = (float*)qn;

  float* hout = out;
  float* cout = out + (size_t)N*H;
  float* aout = cout + (size_t)N*9;   // normalized alpha lives here (e-order)

  k_zero<<<(N + 255)/256, 256, 0, stream>>>((float*)counts, N);
  k_prep_w1<<<32, 256, 0, stream>>>(Wc1, w1f);
  k_hist<<<(E + 255)/256, 256, 0, stream>>>(row, counts, E);
  k_node_proj<KB><<<(N + 3)/4, 384, 0, stream>>>(h, Wq, bq, Wkv, bkv, qn, kn, vn, N);
  k_scan<<<1, 1024, 0, stream>>>(counts, row_start, cursor, N);
  k_scatter<<<(E + 255)/256, 256, 0, stream>>>(row, cursor, eidx, E);
  k_edge_alpha<KB><<<1024, 256, 0, stream>>>(coord, row, col, Wkv, eidx, qn, kn, aout, E);
  k_row_softmax<<<(N + 255)/256, 256, 0, stream>>>(row_start, eidx, aout, N);
  k_edge_mlp<KB><<<(E + 127)/128, 256, 0, stream>>>(coord, row, col, Wkv, Wc2, vn,
                                                    w1f, mlpout, E);
  k_row_final<KB><<<(N + 3)/4, 256, 0, stream>>>(h, coord, col, Wkv, row_start, eidx,
                                                 aout, vn, mlpout, hout, cout, N);
}

extern "C" void kernel_launch(void* const* d_in, const int* in_sizes, int n_in,
                              void* d_out, int out_size, void* d_ws, size_t ws_size,
                              hipStream_t stream)
{
  const float* h     = (const float*)d_in[0];
  const float* coord = (const float*)d_in[1];
  const int* row = (const int*)d_in[2];
  const int* col = (const int*)d_in[3];
  const float* Wq  = (const float*)d_in[4];
  const float* bq  = (const float*)d_in[5];
  const float* Wkv = (const float*)d_in[6];
  const float* bkv = (const float*)d_in[7];
  const float* Wc1 = (const float*)d_in[8];
  const float* Wc2 = (const float*)d_in[9];
  const int N = in_sizes[0] / H;
  const int E = in_sizes[2];
  float* out = (float*)d_out;

  const size_t Epad = (size_t)((E + 127)/128)*128;
  const size_t sortb = (size_t)N*4*3 + 4 + (size_t)E*4;     // counts/start/cursor/eidx
  const size_t w1b   = 8192*16 + 32;
  // mlpout must fit in the dead qn region
  const bool fit_f32 = 3*Epad*4 <= (size_t)N*H*4;
  const bool fit_b16 = 3*Epad*4 <= (size_t)N*H*2;
  const size_t need_f32 = (size_t)N*H*3*4 + sortb + w1b + (fit_f32 ? 0 : 3*Epad*4);
  const size_t need_b16 = (size_t)N*H*3*2 + sortb + w1b + (fit_b16 ? 0 : 3*Epad*4);

  if (ws_size >= need_f32) {
    run_pipeline<false>(h, coord, row, col, Wq, bq, Wkv, bkv, Wc1, Wc2,
                        d_ws, out, N, E, stream);
  } else if (ws_size >= need_b16) {
    run_pipeline<true>(h, coord, row, col, Wq, bq, Wkv, bkv, Wc1, Wc2,
                       d_ws, out, N, E, stream);
  } else {
    k_sentinel<<<(out_size + 255)/256, 256, 0, stream>>>(out, out_size);
  }
}

// Round 8
// 1122.922 us; speedup vs baseline: 1.0339x; 1.0339x over previous
//
#include <hip/hip_runtime.h>

#define H 128
#define KV 256

typedef short bf16x8 __attribute__((ext_vector_type(8)));
typedef float f32x4 __attribute__((ext_vector_type(4)));
union FragU { uint4 u; bf16x8 s; };

__device__ __forceinline__ float bf2f(unsigned short u) {
  return __uint_as_float(((unsigned)u) << 16);
}
__device__ __forceinline__ unsigned short f2bf(float f) {
  unsigned b = __float_as_uint(f);
  b += 0x7FFFu + ((b >> 16) & 1u);   // round-to-nearest-even
  return (unsigned short)(b >> 16);
}

// node-array storage: fp32 (KB=false) or bf16 (KB=true) tier
template<bool KB>
__device__ __forceinline__ float nld(const void* a, size_t idx) {
  if (KB) return bf2f(((const unsigned short*)a)[idx]);
  else    return ((const float*)a)[idx];
}
template<bool KB>
__device__ __forceinline__ void nst(void* a, size_t idx, float v) {
  if (KB) ((unsigned short*)a)[idx] = f2bf(v);
  else    ((float*)a)[idx] = v;
}

__global__ __launch_bounds__(256) void k_zero(float* __restrict__ p, int n) {
  int i = blockIdx.x * 256 + threadIdx.x;
  if (i < n) p[i] = 0.f;
}

__global__ __launch_bounds__(256) void k_sentinel(float* __restrict__ out, int n) {
  int i = blockIdx.x * 256 + threadIdx.x;
  if (i < n) out[i] = 1000.0f;
}

// pack Wc1 (128x512 fp32) into bf16 fragment order (A[m=o][k=v] == B[k][n=o] packing)
__global__ __launch_bounds__(256) void k_prep_w1(const float* __restrict__ Wc1,
                                                 uint4* __restrict__ w1f) {
  int t = blockIdx.x*256 + threadIdx.x;    // 8192 total
  int g = t >> 6, lane = t & 63;
  int q = g >> 5, kk = (g >> 3) & 3, mt = g & 7;
  int o = q*128 + mt*16 + (lane & 15);
  int kbase = kk*32 + (lane >> 4)*8;
  unsigned s[8];
  #pragma unroll
  for (int j = 0; j < 8; ++j) s[j] = f2bf(Wc1[(kbase+j)*512 + o]);
  uint4 u;
  u.x = s[0] | (s[1]<<16); u.y = s[2] | (s[3]<<16);
  u.z = s[4] | (s[5]<<16); u.w = s[6] | (s[7]<<16);
  w1f[g*64 + lane] = u;
}

// ---------- counting sort of edges by row ----------
__global__ __launch_bounds__(256) void k_hist(const int* __restrict__ row,
                                              int* __restrict__ counts, int E) {
  int e = blockIdx.x*256 + threadIdx.x;
  if (e < E) atomicAdd(&counts[row[e]], 1);
}

// single-block exclusive scan (wave-scan + cross-wave), also inits cursor
__global__ __launch_bounds__(1024) void k_scan(const int* __restrict__ counts,
                                               int* __restrict__ row_start,
                                               int* __restrict__ cursor, int n) {
  __shared__ int wsum[16];
  __shared__ int carry_s;
  const int tid = threadIdx.x, lane = tid & 63, wid = tid >> 6;
  if (tid == 0) carry_s = 0;
  __syncthreads();
  for (int base = 0; base < n; base += 1024) {
    int i = base + tid;
    int v = (i < n) ? counts[i] : 0;
    int s = v;
    #pragma unroll
    for (int off = 1; off < 64; off <<= 1) {
      int t = __shfl_up(s, off, 64);
      if (lane >= off) s += t;
    }
    if (lane == 63) wsum[wid] = s;
    __syncthreads();
    if (wid == 0 && lane < 16) {
      int w = wsum[lane];
      #pragma unroll
      for (int off = 1; off < 16; off <<= 1) {
        int t = __shfl_up(w, off, 16);
        if (lane >= off) w += t;
      }
      wsum[lane] = w;
    }
    __syncthreads();
    int wexcl = (wid == 0) ? 0 : wsum[wid-1];
    int excl = carry_s + wexcl + (s - v);
    if (i < n) { row_start[i] = excl; cursor[i] = excl; }
    __syncthreads();
    if (tid == 0) carry_s += wsum[15];
    __syncthreads();
  }
  if (threadIdx.x == 0) row_start[n] = carry_s;
}

__global__ __launch_bounds__(256) void k_scatter(const int* __restrict__ row,
                                                 int* __restrict__ cursor,
                                                 int* __restrict__ eidx, int E) {
  int e = blockIdx.x*256 + threadIdx.x;
  if (e < E) {
    int pos = atomicAdd(&cursor[row[e]], 1);
    eidx[pos] = e;
  }
}

// ---------- K1: qn = h@Wq+bq, kn/vn = deinterleaved h@Wkv[9:]+bkv ----------
template<bool KB>
__global__ __launch_bounds__(384) void k_node_proj(
    const float* __restrict__ h, const float* __restrict__ Wq,
    const float* __restrict__ bq, const float* __restrict__ Wkv,
    const float* __restrict__ bkv, void* __restrict__ qn,
    void* __restrict__ kn, void* __restrict__ vn, int N)
{
  __shared__ float hs[4][H];
  const int n0 = blockIdx.x * 4;
  const int t = threadIdx.x;
  for (int idx = t; idx < 4*H; idx += 384) {
    int nn = idx >> 7, jj = idx & 127;
    hs[nn][jj] = (n0 + nn < N) ? h[(size_t)(n0+nn)*H + jj] : 0.f;
  }
  __syncthreads();
  float a0 = 0.f, a1 = 0.f, a2 = 0.f, a3 = 0.f;
  if (t < H) {
    #pragma unroll 4
    for (int j = 0; j < H; ++j) {
      float w = Wq[j*H + t];
      a0 += hs[0][j]*w; a1 += hs[1][j]*w; a2 += hs[2][j]*w; a3 += hs[3][j]*w;
    }
    float b = bq[t];
    if (n0+0 < N) nst<KB>(qn, (size_t)(n0+0)*H + t, a0 + b);
    if (n0+1 < N) nst<KB>(qn, (size_t)(n0+1)*H + t, a1 + b);
    if (n0+2 < N) nst<KB>(qn, (size_t)(n0+2)*H + t, a2 + b);
    if (n0+3 < N) nst<KB>(qn, (size_t)(n0+3)*H + t, a3 + b);
  } else {
    int c = t - H;                 // column of 2H kv output
    #pragma unroll 4
    for (int j = 0; j < H; ++j) {
      float w = Wkv[(9 + j)*KV + c];
      a0 += hs[0][j]*w; a1 += hs[1][j]*w; a2 += hs[2][j]*w; a3 += hs[3][j]*w;
    }
    float b = bkv[c];
    void* dst = (c & 1) ? vn : kn;
    size_t ch = (size_t)(c >> 1);
    if (n0+0 < N) nst<KB>(dst, (size_t)(n0+0)*H + ch, a0 + b);
    if (n0+1 < N) nst<KB>(dst, (size_t)(n0+1)*H + ch, a1 + b);
    if (n0+2 < N) nst<KB>(dst, (size_t)(n0+2)*H + ch, a2 + b);
    if (n0+3 < N) nst<KB>(dst, (size_t)(n0+3)*H + ch, a3 + b);
  }
}

// ---------- K2: raw alpha per edge (CSR order for qn L1 reuse) ----------
template<bool KB>
__global__ __launch_bounds__(256) void k_edge_alpha(
    const float* __restrict__ coord, const int* __restrict__ row,
    const int* __restrict__ col, const float* __restrict__ Wkv,
    const int* __restrict__ eidx, const void* __restrict__ qn,
    const void* __restrict__ kn, float* __restrict__ aout, int E)
{
  __shared__ float wke[9*128];     // Wkv even cols (k weights for radial)
  const int tid = threadIdx.x;
  for (int idx = tid; idx < 9*128; idx += 256) {
    int p = idx >> 7, j = idx & 127;
    wke[idx] = Wkv[p*KV + 2*j];
  }
  __syncthreads();
  int lane = tid & 63;
  int gw = (blockIdx.x * 256 + tid) >> 6;
  int nw = (gridDim.x * 256) >> 6;
  int chunk = (E + nw - 1) / nw;
  int j0 = gw*chunk, j1 = min(E, j0 + chunk);
  for (int j = j0; j < j1; ++j) {
    int e = eidx[j];               // sorted by row -> qn[r] reused ~deg times
    int r = row[e], c = col[e];
    float cd[9], rad[9];
    #pragma unroll
    for (int i = 0; i < 9; ++i) cd[i] = coord[(size_t)r*9+i] - coord[(size_t)c*9+i];
    #pragma unroll
    for (int a = 0; a < 3; ++a)
      #pragma unroll
      for (int b = 0; b < 3; ++b)
        rad[a*3+b] = cd[a*3]*cd[b*3] + cd[a*3+1]*cd[b*3+1] + cd[a*3+2]*cd[b*3+2];
    float q0 = nld<KB>(qn, (size_t)r*H + lane);
    float q1 = nld<KB>(qn, (size_t)r*H + 64 + lane);
    float k0 = nld<KB>(kn, (size_t)c*H + lane);
    float k1 = nld<KB>(kn, (size_t)c*H + 64 + lane);
    #pragma unroll
    for (int p = 0; p < 9; ++p) {
      k0 += rad[p]*wke[p*128 + lane];
      k1 += rad[p]*wke[p*128 + 64 + lane];
    }
    float acc = q0*k0 + q1*k1;
    #pragma unroll
    for (int m = 32; m > 0; m >>= 1) acc += __shfl_xor(acc, m, 64);
    if (lane == 0) aout[e] = acc;
  }
}

// ---------- K3: per-row softmax normalize (CSR, no atomics) ----------
__global__ __launch_bounds__(256) void k_row_softmax(
    const int* __restrict__ row_start, const int* __restrict__ eidx,
    float* __restrict__ aout, int N)
{
  int r = blockIdx.x*256 + threadIdx.x;
  if (r >= N) return;
  int js = row_start[r], je = row_start[r+1];
  if (js >= je) return;
  float m = -1e30f;
  for (int j = js; j < je; ++j) m = fmaxf(m, aout[eidx[j]]);
  float s = 0.f;
  for (int j = js; j < je; ++j) s += __expf(aout[eidx[j]] - m);
  float inv = 1.f / s;              // s >= 1 (max edge contributes exp(0)=1)
  for (int j = js; j < je; ++j) {
    int ie = eidx[j];
    aout[ie] = __expf(aout[ie] - m) * inv;
  }
}

// ---------- K4: MFMA MLP per 128-edge tile -> mlpout[e][3] ----------
// Transposed GEMM: hidden^T[o][edge] = Wc1^T @ V^T. C-layout gives each lane
// 4 o-values of ONE edge -> cv accumulates thread-locally; only a 2-level
// cross-quad shuffle at the end (no per-quarter reduction storms).
#define EST 10   // einfo stride: rad[0..8] c[9]
template<bool KB>
__global__ __launch_bounds__(256) void k_edge_mlp(
    const float* __restrict__ coord, const int* __restrict__ row,
    const int* __restrict__ col, const float* __restrict__ Wkv,
    const float* __restrict__ Wc2, const void* __restrict__ vn,
    const uint4* __restrict__ w1f, float* __restrict__ mlpout, int E)
{
  __shared__ unsigned vt[128*64];     // 32KB: V tile bf16x2, 16B-chunk XOR swizzle
  __shared__ float einfo[128*EST];    // 5KB
  __shared__ float2 wvo2[9*64];       // 4.5KB: Wkv odd cols paired per lane
  __shared__ float wc2p[512*4];       // 8KB: Wc2 padded [o][4] for b128 reads
  const int tid = threadIdx.x;
  const int wid = tid >> 6, lane = tid & 63;
  const int quad = lane >> 4, colc = lane & 15;

  for (int idx = tid; idx < 9*64; idx += 256) {
    int p = idx / 64, l = idx - p*64;
    wvo2[idx] = make_float2(Wkv[p*KV + 4*l + 1], Wkv[p*KV + 4*l + 3]);
  }
  for (int idx = tid; idx < 512*4; idx += 256) {
    int o = idx >> 2, ch = idx & 3;
    wc2p[idx] = (ch < 3) ? Wc2[o*3 + ch] : 0.f;
  }

  // ---- phase 1: edge info ----
  const int e0 = blockIdx.x * 128;
  if (tid < 128) {
    int e = e0 + tid;
    float* ei = &einfo[tid*EST];
    if (e < E) {
      int r = row[e], c = col[e];
      float cd[9];
      #pragma unroll
      for (int i = 0; i < 9; ++i) cd[i] = coord[(size_t)r*9+i] - coord[(size_t)c*9+i];
      #pragma unroll
      for (int a = 0; a < 3; ++a)
        #pragma unroll
        for (int b = 0; b < 3; ++b)
          ei[a*3+b] = cd[a*3]*cd[b*3] + cd[a*3+1]*cd[b*3+1] + cd[a*3+2]*cd[b*3+2];
      ei[9] = __int_as_float(c);
    } else {
      #pragma unroll
      for (int i = 0; i < EST; ++i) ei[i] = 0.f;   // rad=0, c=0 -> inert
    }
  }
  __syncthreads();

  // ---- phase 2: V tile (each wave one edge per iteration) ----
  const float2* vn2 = (const float2*)vn;   // fp32 tier: pairs (2*lane, 2*lane+1)
  for (int i = 0; i < 32; ++i) {
    int el = i*4 + wid;
    const float* ei = &einfo[el*EST];
    float rad[9];
    #pragma unroll
    for (int p = 0; p < 9; ++p) rad[p] = ei[p];
    int c = __float_as_int(ei[9]);
    float v0, v1;
    if (KB) {
      v0 = nld<KB>(vn, (size_t)c*H + 2*lane);
      v1 = nld<KB>(vn, (size_t)c*H + 2*lane + 1);
    } else {
      float2 v2 = vn2[(size_t)c*64 + lane];
      v0 = v2.x; v1 = v2.y;
    }
    #pragma unroll
    for (int p = 0; p < 9; ++p) {
      float2 w = wvo2[p*64 + lane];
      v0 += rad[p]*w.x; v1 += rad[p]*w.y;
    }
    unsigned pk = (unsigned)f2bf(v0) | ((unsigned)f2bf(v1) << 16);
    vt[el*64 + (((lane>>2) ^ (el&15))<<2) + (lane&3)] = pk;
  }
  __syncthreads();

  // ---- phase 3: transposed MFMA GEMM + thread-local cv epilogue ----
  const int ntbase = wid*32;   // wave owns edges [ntbase, ntbase+32)
  float cv[2][3] = {{0.f,0.f,0.f},{0.f,0.f,0.f}};
  for (int q = 0; q < 4; ++q) {
    f32x4 acc[8][2];
    #pragma unroll
    for (int mt = 0; mt < 8; ++mt)
      #pragma unroll
      for (int nt = 0; nt < 2; ++nt) acc[mt][nt] = (f32x4){0.f,0.f,0.f,0.f};
    #pragma unroll
    for (int kk = 0; kk < 4; ++kk) {
      FragU bfr[2];
      #pragma unroll
      for (int nt = 0; nt < 2; ++nt) {
        int rrow = ntbase + nt*16 + colc;
        int chunk = kk*4 + quad;
        bfr[nt].u = *((const uint4*)&vt[rrow*64 + ((chunk ^ (rrow&15))<<2)]);
      }
      #pragma unroll
      for (int mt = 0; mt < 8; ++mt) {
        FragU afr;
        afr.u = w1f[(((q*4+kk)*8+mt)<<6) + lane];
        #pragma unroll
        for (int nt = 0; nt < 2; ++nt)
          acc[mt][nt] = __builtin_amdgcn_mfma_f32_16x16x32_bf16(
              afr.s, bfr[nt].s, acc[mt][nt], 0, 0, 0);
      }
    }
    // epilogue: lane holds hidden^T[o=mt*16+quad*4+g][edge=ntbase+nt*16+colc]
    #pragma unroll
    for (int mt = 0; mt < 8; ++mt) {
      int obase = q*128 + mt*16 + quad*4;
      #pragma unroll
      for (int g = 0; g < 4; ++g) {
        const float4 w = *((const float4*)&wc2p[(obase + g)*4]);
        #pragma unroll
        for (int nt = 0; nt < 2; ++nt) {
          float s = acc[mt][nt][g];
          float hs = s / (1.f + __expf(-s));   // silu
          cv[nt][0] += hs*w.x; cv[nt][1] += hs*w.y; cv[nt][2] += hs*w.z;
        }
      }
    }
  }
  // reduce over the 4 quads (disjoint o-coverage, same edge per col)
  #pragma unroll
  for (int nt = 0; nt < 2; ++nt)
    #pragma unroll
    for (int ch = 0; ch < 3; ++ch) {
      cv[nt][ch] += __shfl_xor(cv[nt][ch], 16, 64);
      cv[nt][ch] += __shfl_xor(cv[nt][ch], 32, 64);
    }
  if (quad == 0) {
    #pragma unroll
    for (int nt = 0; nt < 2; ++nt) {
      int e = e0 + ntbase + nt*16 + colc;
      if (e < E) {
        mlpout[(size_t)e*3 + 0] = cv[nt][0];
        mlpout[(size_t)e*3 + 1] = cv[nt][1];
        mlpout[(size_t)e*3 + 2] = cv[nt][2];
      }
    }
  }
}

// ---------- K5: per-row h_out AND coord_out (CSR, atomic-free) ----------
template<bool KB>
__global__ __launch_bounds__(256) void k_row_final(
    const float* __restrict__ h, const float* __restrict__ coord,
    const int* __restrict__ col, const float* __restrict__ Wkv,
    const int* __restrict__ row_start, const int* __restrict__ eidx,
    const float* __restrict__ aout, const void* __restrict__ vn,
    const float* __restrict__ mlpout, float* __restrict__ hout,
    float* __restrict__ cout, int N)
{
  __shared__ float wvo[9*128];     // Wkv odd cols (v weights for radial)
  const int tid = threadIdx.x;
  for (int idx = tid; idx < 9*128; idx += 256) {
    int p = idx >> 7, j = idx & 127;
    wvo[idx] = Wkv[p*KV + 2*j + 1];
  }
  __syncthreads();
  const int wid = tid >> 6, lane = tid & 63;
  const int r = blockIdx.x*4 + wid;
  if (r >= N) return;
  int js = row_start[r], je = row_start[r+1];
  float cr[9];
  #pragma unroll
  for (int i = 0; i < 9; ++i) cr[i] = coord[(size_t)r*9 + i];
  float acc0 = 0.f, acc1 = 0.f;
  float t[9], cg[9];
  #pragma unroll
  for (int p = 0; p < 9; ++p) { t[p] = 0.f; cg[p] = 0.f; }
  for (int j = js; j < je; ++j) {
    int ie = eidx[j];
    float a = aout[ie];
    int c = col[ie];
    float cd[9], rad[9];
    #pragma unroll
    for (int i = 0; i < 9; ++i) cd[i] = cr[i] - coord[(size_t)c*9+i];
    #pragma unroll
    for (int aa = 0; aa < 3; ++aa)
      #pragma unroll
      for (int bb = 0; bb < 3; ++bb)
        rad[aa*3+bb] = cd[aa*3]*cd[bb*3] + cd[aa*3+1]*cd[bb*3+1] + cd[aa*3+2]*cd[bb*3+2];
    acc0 += a * nld<KB>(vn, (size_t)c*H + 2*lane);
    acc1 += a * nld<KB>(vn, (size_t)c*H + 2*lane + 1);
    #pragma unroll
    for (int p = 0; p < 9; ++p) t[p] += a * rad[p];
    float cv0 = a * mlpout[(size_t)ie*3 + 0];
    float cv1 = a * mlpout[(size_t)ie*3 + 1];
    float cv2 = a * mlpout[(size_t)ie*3 + 2];
    #pragma unroll
    for (int d = 0; d < 3; ++d) {
      cg[0+d] += cv0 * cd[0+d];
      cg[3+d] += cv1 * cd[3+d];
      cg[6+d] += cv2 * cd[6+d];
    }
  }
  #pragma unroll
  for (int p = 0; p < 9; ++p) {
    acc0 += t[p] * wvo[p*128 + 2*lane];
    acc1 += t[p] * wvo[p*128 + 2*lane + 1];
  }
  hout[(size_t)r*H + 2*lane]     = h[(size_t)r*H + 2*lane]     + acc0;
  hout[(size_t)r*H + 2*lane + 1] = h[(size_t)r*H + 2*lane + 1] + acc1;
  if (lane == 0) {
    #pragma unroll
    for (int i = 0; i < 9; ++i) {
      float x = fminf(10.f, fmaxf(-10.f, cg[i]));
      cout[(size_t)r*9 + i] = cr[i] + x;
    }
  }
}

template<bool KB>
static void run_pipeline(const float* h, const float* coord,
                         const int* row, const int* col,
                         const float* Wq, const float* bq,
                         const float* Wkv, const float* bkv,
                         const float* Wc1, const float* Wc2,
                         void* d_ws, float* out, int N, int E,
                         hipStream_t stream)
{
  const size_t es = KB ? 2 : 4;
  char* p = (char*)d_ws;
  void* kn = p;                    p += (size_t)N*H*es;
  void* vn = p;                    p += (size_t)N*H*es;
  void* qn = p;                    p += (size_t)N*H*es;   // dead after alpha
  int* counts = (int*)p;           p += (size_t)N*4;
  int* row_start = (int*)p;        p += (size_t)(N+1)*4;
  int* cursor = (int*)p;           p += (size_t)N*4;
  int* eidx = (int*)p;             p += (size_t)E*4;
  uint4* w1f = (uint4*)((((size_t)p) + 15) & ~(size_t)15);
  // mlpout aliases qn (dead after k_edge_alpha); fits: 3*Epad*4 <= N*H*es
  float* mlpout = (float*)qn;

  float* hout = out;
  float* cout = out + (size_t)N*H;
  float* aout = cout + (size_t)N*9;   // normalized alpha lives here (e-order)

  k_zero<<<(N + 255)/256, 256, 0, stream>>>((float*)counts, N);
  k_prep_w1<<<32, 256, 0, stream>>>(Wc1, w1f);
  k_hist<<<(E + 255)/256, 256, 0, stream>>>(row, counts, E);
  k_node_proj<KB><<<(N + 3)/4, 384, 0, stream>>>(h, Wq, bq, Wkv, bkv, qn, kn, vn, N);
  k_scan<<<1, 1024, 0, stream>>>(counts, row_start, cursor, N);
  k_scatter<<<(E + 255)/256, 256, 0, stream>>>(row, cursor, eidx, E);
  k_edge_alpha<KB><<<1024, 256, 0, stream>>>(coord, row, col, Wkv, eidx, qn, kn, aout, E);
  k_row_softmax<<<(N + 255)/256, 256, 0, stream>>>(row_start, eidx, aout, N);
  k_edge_mlp<KB><<<(E + 127)/128, 256, 0, stream>>>(coord, row, col, Wkv, Wc2, vn,
                                                    w1f, mlpout, E);
  k_row_final<KB><<<(N + 3)/4, 256, 0, stream>>>(h, coord, col, Wkv, row_start, eidx,
                                                 aout, vn, mlpout, hout, cout, N);
}

extern "C" void kernel_launch(void* const* d_in, const int* in_sizes, int n_in,
                              void* d_out, int out_size, void* d_ws, size_t ws_size,
                              hipStream_t stream)
{
  const float* h     = (const float*)d_in[0];
  const float* coord = (const float*)d_in[1];
  const int* row = (const int*)d_in[2];
  const int* col = (const int*)d_in[3];
  const float* Wq  = (const float*)d_in[4];
  const float* bq  = (const float*)d_in[5];
  const float* Wkv = (const float*)d_in[6];
  const float* bkv = (const float*)d_in[7];
  const float* Wc1 = (const float*)d_in[8];
  const float* Wc2 = (const float*)d_in[9];
  const int N = in_sizes[0] / H;
  const int E = in_sizes[2];
  float* out = (float*)d_out;

  const size_t Epad = (size_t)((E + 127)/128)*128;
  const size_t sortb = (size_t)N*4*3 + 4 + (size_t)E*4;     // counts/start/cursor/eidx
  const size_t w1b   = 8192*16 + 32;
  // mlpout must fit in the dead qn region
  const bool fit_f32 = 3*Epad*4 <= (size_t)N*H*4;
  const bool fit_b16 = 3*Epad*4 <= (size_t)N*H*2;
  const size_t need_f32 = (size_t)N*H*3*4 + sortb + w1b + (fit_f32 ? 0 : 3*Epad*4);
  const size_t need_b16 = (size_t)N*H*3*2 + sortb + w1b + (fit_b16 ? 0 : 3*Epad*4);

  if (ws_size >= need_f32) {
    run_pipeline<false>(h, coord, row, col, Wq, bq, Wkv, bkv, Wc1, Wc2,
                        d_ws, out, N, E, stream);
  } else if (ws_size >= need_b16) {
    run_pipeline<true>(h, coord, row, col, Wq, bq, Wkv, bkv, Wc1, Wc2,
                       d_ws, out, N, E, stream);
  } else {
    k_sentinel<<<(out_size + 255)/256, 256, 0, stream>>>(out, out_size);
  }
}

// Round 9
// 986.136 us; speedup vs baseline: 1.1773x; 1.1387x over previous
//
#include <hip/hip_runtime.h>

#define H 128
#define KV 256

typedef short bf16x8 __attribute__((ext_vector_type(8)));
typedef float f32x4 __attribute__((ext_vector_type(4)));
union FragU { uint4 u; bf16x8 s; };

__device__ __forceinline__ float bf2f(unsigned short u) {
  return __uint_as_float(((unsigned)u) << 16);
}
__device__ __forceinline__ unsigned short f2bf(float f) {
  unsigned b = __float_as_uint(f);
  b += 0x7FFFu + ((b >> 16) & 1u);   // round-to-nearest-even
  return (unsigned short)(b >> 16);
}

__global__ __launch_bounds__(256) void k_zero(float* __restrict__ p, int n) {
  int i = blockIdx.x * 256 + threadIdx.x;
  if (i < n) p[i] = 0.f;
}

__global__ __launch_bounds__(256) void k_sentinel(float* __restrict__ out, int n) {
  int i = blockIdx.x * 256 + threadIdx.x;
  if (i < n) out[i] = 1000.0f;
}

// pack Wc1 (128x512 fp32) into bf16 fragment order (verified layout from R5-R8)
__global__ __launch_bounds__(256) void k_prep_w1(const float* __restrict__ Wc1,
                                                 uint4* __restrict__ w1f) {
  int t = blockIdx.x*256 + threadIdx.x;    // 8192 total
  int g = t >> 6, lane = t & 63;
  int q = g >> 5, kk = (g >> 3) & 3, mt = g & 7;
  int o = q*128 + mt*16 + (lane & 15);
  int kbase = kk*32 + (lane >> 4)*8;
  unsigned s[8];
  #pragma unroll
  for (int j = 0; j < 8; ++j) s[j] = f2bf(Wc1[(kbase+j)*512 + o]);
  uint4 u;
  u.x = s[0] | (s[1]<<16); u.y = s[2] | (s[3]<<16);
  u.z = s[4] | (s[5]<<16); u.w = s[6] | (s[7]<<16);
  w1f[g*64 + lane] = u;
}

// Wr[9][512] = Wvo @ Wc1  (Wvo = odd cols of Wkv radial rows)
__global__ __launch_bounds__(256) void k_prep_wr(const float* __restrict__ Wkv,
                                                 const float* __restrict__ Wc1,
                                                 float* __restrict__ Wr) {
  int idx = blockIdx.x*256 + threadIdx.x;   // 4608
  if (idx >= 9*512) return;
  int p = idx >> 9, o = idx & 511;
  float s = 0.f;
  for (int k = 0; k < 128; ++k) s += Wkv[p*KV + 2*k + 1] * Wc1[k*512 + o];
  Wr[p*512 + o] = s;
}

// ---------- counting sort of edges by row ----------
__global__ __launch_bounds__(256) void k_hist(const int* __restrict__ row,
                                              int* __restrict__ counts, int E) {
  int e = blockIdx.x*256 + threadIdx.x;
  if (e < E) atomicAdd(&counts[row[e]], 1);
}

__global__ __launch_bounds__(1024) void k_scan(const int* __restrict__ counts,
                                               int* __restrict__ row_start,
                                               int* __restrict__ cursor, int n) {
  __shared__ int wsum[16];
  __shared__ int carry_s;
  const int tid = threadIdx.x, lane = tid & 63, wid = tid >> 6;
  if (tid == 0) carry_s = 0;
  __syncthreads();
  for (int base = 0; base < n; base += 1024) {
    int i = base + tid;
    int v = (i < n) ? counts[i] : 0;
    int s = v;
    #pragma unroll
    for (int off = 1; off < 64; off <<= 1) {
      int t = __shfl_up(s, off, 64);
      if (lane >= off) s += t;
    }
    if (lane == 63) wsum[wid] = s;
    __syncthreads();
    if (wid == 0 && lane < 16) {
      int w = wsum[lane];
      #pragma unroll
      for (int off = 1; off < 16; off <<= 1) {
        int t = __shfl_up(w, off, 16);
        if (lane >= off) w += t;
      }
      wsum[lane] = w;
    }
    __syncthreads();
    int wexcl = (wid == 0) ? 0 : wsum[wid-1];
    int excl = carry_s + wexcl + (s - v);
    if (i < n) { row_start[i] = excl; cursor[i] = excl; }
    __syncthreads();
    if (tid == 0) carry_s += wsum[15];
    __syncthreads();
  }
  if (threadIdx.x == 0) row_start[n] = carry_s;
}

__global__ __launch_bounds__(256) void k_scatter(const int* __restrict__ row,
                                                 int* __restrict__ cursor,
                                                 int* __restrict__ eidx, int E) {
  int e = blockIdx.x*256 + threadIdx.x;
  if (e < E) {
    int pos = atomicAdd(&cursor[row[e]], 1);
    eidx[pos] = e;
  }
}

// ---------- K1: qn/kn fp32, vn bf16 ----------
__global__ __launch_bounds__(384) void k_node_proj(
    const float* __restrict__ h, const float* __restrict__ Wq,
    const float* __restrict__ bq, const float* __restrict__ Wkv,
    const float* __restrict__ bkv, float* __restrict__ qn,
    float* __restrict__ kn, unsigned short* __restrict__ vn, int N)
{
  __shared__ float hs[4][H];
  const int n0 = blockIdx.x * 4;
  const int t = threadIdx.x;
  for (int idx = t; idx < 4*H; idx += 384) {
    int nn = idx >> 7, jj = idx & 127;
    hs[nn][jj] = (n0 + nn < N) ? h[(size_t)(n0+nn)*H + jj] : 0.f;
  }
  __syncthreads();
  float a0 = 0.f, a1 = 0.f, a2 = 0.f, a3 = 0.f;
  if (t < H) {
    #pragma unroll 4
    for (int j = 0; j < H; ++j) {
      float w = Wq[j*H + t];
      a0 += hs[0][j]*w; a1 += hs[1][j]*w; a2 += hs[2][j]*w; a3 += hs[3][j]*w;
    }
    float b = bq[t];
    if (n0+0 < N) qn[(size_t)(n0+0)*H + t] = a0 + b;
    if (n0+1 < N) qn[(size_t)(n0+1)*H + t] = a1 + b;
    if (n0+2 < N) qn[(size_t)(n0+2)*H + t] = a2 + b;
    if (n0+3 < N) qn[(size_t)(n0+3)*H + t] = a3 + b;
  } else {
    int c = t - H;                 // column of 2H kv output
    #pragma unroll 4
    for (int j = 0; j < H; ++j) {
      float w = Wkv[(9 + j)*KV + c];
      a0 += hs[0][j]*w; a1 += hs[1][j]*w; a2 += hs[2][j]*w; a3 += hs[3][j]*w;
    }
    float b = bkv[c];
    size_t ch = (size_t)(c >> 1);
    if (c & 1) {
      if (n0+0 < N) vn[(size_t)(n0+0)*H + ch] = f2bf(a0 + b);
      if (n0+1 < N) vn[(size_t)(n0+1)*H + ch] = f2bf(a1 + b);
      if (n0+2 < N) vn[(size_t)(n0+2)*H + ch] = f2bf(a2 + b);
      if (n0+3 < N) vn[(size_t)(n0+3)*H + ch] = f2bf(a3 + b);
    } else {
      if (n0+0 < N) kn[(size_t)(n0+0)*H + ch] = a0 + b;
      if (n0+1 < N) kn[(size_t)(n0+1)*H + ch] = a1 + b;
      if (n0+2 < N) kn[(size_t)(n0+2)*H + ch] = a2 + b;
      if (n0+3 < N) kn[(size_t)(n0+3)*H + ch] = a3 + b;
    }
  }
}

// ---------- K2: raw alpha per edge (CSR order for qn L1 reuse) ----------
__global__ __launch_bounds__(256) void k_edge_alpha(
    const float* __restrict__ coord, const int* __restrict__ row,
    const int* __restrict__ col, const float* __restrict__ Wkv,
    const int* __restrict__ eidx, const float* __restrict__ qn,
    const float* __restrict__ kn, float* __restrict__ aout, int E)
{
  __shared__ float wke[9*128];     // Wkv even cols (k weights for radial)
  const int tid = threadIdx.x;
  for (int idx = tid; idx < 9*128; idx += 256) {
    int p = idx >> 7, j = idx & 127;
    wke[idx] = Wkv[p*KV + 2*j];
  }
  __syncthreads();
  int lane = tid & 63;
  int gw = (blockIdx.x * 256 + tid) >> 6;
  int nw = (gridDim.x * 256) >> 6;
  int chunk = (E + nw - 1) / nw;
  int j0 = gw*chunk, j1 = min(E, j0 + chunk);
  for (int j = j0; j < j1; ++j) {
    int e = eidx[j];               // sorted by row -> qn[r] reused ~deg times
    int r = row[e], c = col[e];
    float cd[9], rad[9];
    #pragma unroll
    for (int i = 0; i < 9; ++i) cd[i] = coord[(size_t)r*9+i] - coord[(size_t)c*9+i];
    #pragma unroll
    for (int a = 0; a < 3; ++a)
      #pragma unroll
      for (int b = 0; b < 3; ++b)
        rad[a*3+b] = cd[a*3]*cd[b*3] + cd[a*3+1]*cd[b*3+1] + cd[a*3+2]*cd[b*3+2];
    float q0 = qn[(size_t)r*H + lane];
    float q1 = qn[(size_t)r*H + 64 + lane];
    float k0 = kn[(size_t)c*H + lane];
    float k1 = kn[(size_t)c*H + 64 + lane];
    #pragma unroll
    for (int p = 0; p < 9; ++p) {
      k0 += rad[p]*wke[p*128 + lane];
      k1 += rad[p]*wke[p*128 + 64 + lane];
    }
    float acc = q0*k0 + q1*k1;
    #pragma unroll
    for (int m = 32; m > 0; m >>= 1) acc += __shfl_xor(acc, m, 64);
    if (lane == 0) aout[e] = acc;
  }
}

// ---------- K3: per-row softmax normalize ----------
__global__ __launch_bounds__(256) void k_row_softmax(
    const int* __restrict__ row_start, const int* __restrict__ eidx,
    float* __restrict__ aout, int N)
{
  int r = blockIdx.x*256 + threadIdx.x;
  if (r >= N) return;
  int js = row_start[r], je = row_start[r+1];
  if (js >= je) return;
  float m = -1e30f;
  for (int j = js; j < je; ++j) m = fmaxf(m, aout[eidx[j]]);
  float s = 0.f;
  for (int j = js; j < je; ++j) s += __expf(aout[eidx[j]] - m);
  float inv = 1.f / s;
  for (int j = js; j < je; ++j) {
    int ie = eidx[j];
    aout[ie] = __expf(aout[ie] - m) * inv;
  }
}

// ---------- K4a: hn[N][512] bf16 = vn @ Wc1 (node-level MFMA GEMM) ----------
__global__ __launch_bounds__(256) void k_node_hn(
    const unsigned* __restrict__ vnu,      // vn bf16 viewed as dwords [N][64]
    const uint4* __restrict__ w1f,
    unsigned short* __restrict__ hn, int N)
{
  __shared__ unsigned vt[128*64];          // 32KB swizzled bf16x2 node tile
  __shared__ unsigned short hno[128*128];  // 32KB quarter o-tile
  const int tid = threadIdx.x;
  const int wid = tid >> 6, lane = tid & 63;
  const int quad = lane >> 4, colc = lane & 15;
  const int n0 = blockIdx.x * 128;
  for (int i = 0; i < 32; ++i) {
    int el = i*4 + wid;
    int c = n0 + el; if (c >= N) c = N - 1;
    unsigned pk = vnu[(size_t)c*64 + lane];   // already bf16 pair (2l,2l+1)
    vt[el*64 + (((lane>>2) ^ (el&15))<<2) + (lane&3)] = pk;
  }
  __syncthreads();
  const int ntbase = wid*32;
  for (int q = 0; q < 4; ++q) {
    f32x4 acc[8][2];
    #pragma unroll
    for (int mt = 0; mt < 8; ++mt)
      #pragma unroll
      for (int nt = 0; nt < 2; ++nt) acc[mt][nt] = (f32x4){0.f,0.f,0.f,0.f};
    #pragma unroll
    for (int kk = 0; kk < 4; ++kk) {
      FragU bfr[2];
      #pragma unroll
      for (int nt = 0; nt < 2; ++nt) {
        int rrow = ntbase + nt*16 + colc;
        int chunk = kk*4 + quad;
        bfr[nt].u = *((const uint4*)&vt[rrow*64 + ((chunk ^ (rrow&15))<<2)]);
      }
      #pragma unroll
      for (int mt = 0; mt < 8; ++mt) {
        FragU afr;
        afr.u = w1f[(((q*4+kk)*8+mt)<<6) + lane];
        #pragma unroll
        for (int nt = 0; nt < 2; ++nt)
          acc[mt][nt] = __builtin_amdgcn_mfma_f32_16x16x32_bf16(
              afr.s, bfr[nt].s, acc[mt][nt], 0, 0, 0);
      }
    }
    // lane holds hnT[o=q*128+mt*16+quad*4+g][node=ntbase+nt*16+colc]
    #pragma unroll
    for (int mt = 0; mt < 8; ++mt)
      #pragma unroll
      for (int nt = 0; nt < 2; ++nt) {
        int node = ntbase + nt*16 + colc;
        int o = mt*16 + quad*4;
        unsigned lo = (unsigned)f2bf(acc[mt][nt][0]) | ((unsigned)f2bf(acc[mt][nt][1]) << 16);
        unsigned hi = (unsigned)f2bf(acc[mt][nt][2]) | ((unsigned)f2bf(acc[mt][nt][3]) << 16);
        *((uint2*)&hno[node*128 + o]) = make_uint2(lo, hi);
      }
    __syncthreads();
    const uint4* hns = (const uint4*)hno;    // 128 nodes x 16 uint4
    #pragma unroll
    for (int it = 0; it < 8; ++it) {
      int u = it*256 + tid;
      int node = u >> 4, within = u & 15;
      int gn = n0 + node;
      if (gn < N) ((uint4*)hn)[(size_t)gn*64 + q*16 + within] = hns[node*16 + within];
    }
    __syncthreads();
  }
}

// ---------- K4b: mlpout[e][3] = silu(hn[col] + rad@Wr) @ Wc2 ----------
// wave-per-edge, batch-4 gathers for latency; Wr/Wc2 columns in registers
// (o = lane*8 + j is lane-fixed).
__global__ __launch_bounds__(256) void k_edge_mlp2(
    const float* __restrict__ coord, const int* __restrict__ row,
    const int* __restrict__ col, const float* __restrict__ Wr,
    const float* __restrict__ Wc2, const uint4* __restrict__ hn4,
    float* __restrict__ mlpout, int E)
{
  const int tid = threadIdx.x, wid = tid >> 6, lane = tid & 63;
  float wr[9][8], w2r[8][3];
  #pragma unroll
  for (int p = 0; p < 9; ++p)
    #pragma unroll
    for (int j = 0; j < 8; ++j) wr[p][j] = Wr[p*512 + lane*8 + j];
  #pragma unroll
  for (int j = 0; j < 8; ++j) {
    w2r[j][0] = Wc2[(lane*8+j)*3 + 0];
    w2r[j][1] = Wc2[(lane*8+j)*3 + 1];
    w2r[j][2] = Wc2[(lane*8+j)*3 + 2];
  }
  int gw = blockIdx.x*4 + wid;
  int nw = gridDim.x*4;
  int chunk = (E + nw - 1)/nw;
  int e0 = gw*chunk, e1 = min(E, e0 + chunk);
  for (int e = e0; e < e1; e += 4) {
    int nb = min(4, e1 - e);
    float rad[4][9]; uint4 hh[4];
    #pragma unroll
    for (int k = 0; k < 4; ++k) {
      int ek = (k < nb) ? e + k : e;
      int r = row[ek], c = col[ek];
      hh[k] = hn4[(size_t)c*64 + lane];
      float cd[9];
      #pragma unroll
      for (int i = 0; i < 9; ++i) cd[i] = coord[(size_t)r*9+i] - coord[(size_t)c*9+i];
      #pragma unroll
      for (int a = 0; a < 3; ++a)
        #pragma unroll
        for (int b = 0; b < 3; ++b)
          rad[k][a*3+b] = cd[a*3]*cd[b*3] + cd[a*3+1]*cd[b*3+1] + cd[a*3+2]*cd[b*3+2];
    }
    #pragma unroll
    for (int k = 0; k < 4; ++k) {
      unsigned uu[4] = {hh[k].x, hh[k].y, hh[k].z, hh[k].w};
      float cv0 = 0.f, cv1 = 0.f, cv2 = 0.f;
      #pragma unroll
      for (int d = 0; d < 4; ++d) {
        float s0 = __uint_as_float(uu[d] << 16);
        float s1 = __uint_as_float(uu[d] & 0xffff0000u);
        int ja = d*2, jb = d*2 + 1;
        #pragma unroll
        for (int p = 0; p < 9; ++p) {
          s0 += rad[k][p]*wr[p][ja];
          s1 += rad[k][p]*wr[p][jb];
        }
        s0 = s0 / (1.f + __expf(-s0));
        s1 = s1 / (1.f + __expf(-s1));
        cv0 += s0*w2r[ja][0] + s1*w2r[jb][0];
        cv1 += s0*w2r[ja][1] + s1*w2r[jb][1];
        cv2 += s0*w2r[ja][2] + s1*w2r[jb][2];
      }
      #pragma unroll
      for (int m = 32; m > 0; m >>= 1) {
        cv0 += __shfl_xor(cv0, m, 64);
        cv1 += __shfl_xor(cv1, m, 64);
        cv2 += __shfl_xor(cv2, m, 64);
      }
      if (lane == 0 && k < nb) {
        float* mp = &mlpout[(size_t)(e + k)*3];
        mp[0] = cv0; mp[1] = cv1; mp[2] = cv2;
      }
    }
  }
}

// ---------- K5: per-row h_out AND coord_out (CSR, bf16 vn, unroll-2) ----------
__global__ __launch_bounds__(256) void k_row_final(
    const float* __restrict__ h, const float* __restrict__ coord,
    const int* __restrict__ col, const float* __restrict__ Wkv,
    const int* __restrict__ row_start, const int* __restrict__ eidx,
    const float* __restrict__ aout, const unsigned* __restrict__ vnu,
    const float* __restrict__ mlpout, float* __restrict__ hout,
    float* __restrict__ cout, int N)
{
  __shared__ float wvo[9*128];
  const int tid = threadIdx.x;
  for (int idx = tid; idx < 9*128; idx += 256) {
    int p = idx >> 7, j = idx & 127;
    wvo[idx] = Wkv[p*KV + 2*j + 1];
  }
  __syncthreads();
  const int wid = tid >> 6, lane = tid & 63;
  const int r = blockIdx.x*4 + wid;
  if (r >= N) return;
  int js = row_start[r], je = row_start[r+1];
  float cr[9];
  #pragma unroll
  for (int i = 0; i < 9; ++i) cr[i] = coord[(size_t)r*9 + i];
  float acc0 = 0.f, acc1 = 0.f;
  float t[9], cg[9];
  #pragma unroll
  for (int p = 0; p < 9; ++p) { t[p] = 0.f; cg[p] = 0.f; }
  for (int j = js; j < je; j += 2) {
    int ie0 = eidx[j];
    bool has1 = (j + 1 < je);
    int ie1 = has1 ? eidx[j+1] : ie0;
    int c0 = col[ie0], c1 = col[ie1];
    float a0 = aout[ie0];
    float a1 = has1 ? aout[ie1] : 0.f;
    unsigned v0 = vnu[(size_t)c0*64 + lane];
    unsigned v1 = vnu[(size_t)c1*64 + lane];
    float m00 = mlpout[(size_t)ie0*3+0], m01 = mlpout[(size_t)ie0*3+1], m02 = mlpout[(size_t)ie0*3+2];
    float m10 = mlpout[(size_t)ie1*3+0], m11 = mlpout[(size_t)ie1*3+1], m12 = mlpout[(size_t)ie1*3+2];
    float cd0[9], cd1[9];
    #pragma unroll
    for (int i = 0; i < 9; ++i) {
      cd0[i] = cr[i] - coord[(size_t)c0*9+i];
      cd1[i] = cr[i] - coord[(size_t)c1*9+i];
    }
    #pragma unroll
    for (int aa = 0; aa < 3; ++aa)
      #pragma unroll
      for (int bb = 0; bb < 3; ++bb) {
        float r0 = cd0[aa*3]*cd0[bb*3] + cd0[aa*3+1]*cd0[bb*3+1] + cd0[aa*3+2]*cd0[bb*3+2];
        float r1 = cd1[aa*3]*cd1[bb*3] + cd1[aa*3+1]*cd1[bb*3+1] + cd1[aa*3+2]*cd1[bb*3+2];
        t[aa*3+bb] += a0*r0 + a1*r1;
      }
    acc0 += a0*__uint_as_float(v0 << 16)         + a1*__uint_as_float(v1 << 16);
    acc1 += a0*__uint_as_float(v0 & 0xffff0000u) + a1*__uint_as_float(v1 & 0xffff0000u);
    float p00 = a0*m00, p01 = a0*m01, p02 = a0*m02;
    float p10 = a1*m10, p11 = a1*m11, p12 = a1*m12;
    #pragma unroll
    for (int d = 0; d < 3; ++d) {
      cg[0+d] += p00*cd0[0+d] + p10*cd1[0+d];
      cg[3+d] += p01*cd0[3+d] + p11*cd1[3+d];
      cg[6+d] += p02*cd0[6+d] + p12*cd1[6+d];
    }
  }
  #pragma unroll
  for (int p = 0; p < 9; ++p) {
    acc0 += t[p] * wvo[p*128 + 2*lane];
    acc1 += t[p] * wvo[p*128 + 2*lane + 1];
  }
  hout[(size_t)r*H + 2*lane]     = h[(size_t)r*H + 2*lane]     + acc0;
  hout[(size_t)r*H + 2*lane + 1] = h[(size_t)r*H + 2*lane + 1] + acc1;
  if (lane == 0) {
    #pragma unroll
    for (int i = 0; i < 9; ++i) {
      float x = fminf(10.f, fmaxf(-10.f, cg[i]));
      cout[(size_t)r*9 + i] = cr[i] + x;
    }
  }
}

extern "C" void kernel_launch(void* const* d_in, const int* in_sizes, int n_in,
                              void* d_out, int out_size, void* d_ws, size_t ws_size,
                              hipStream_t stream)
{
  const float* h     = (const float*)d_in[0];
  const float* coord = (const float*)d_in[1];
  const int* row = (const int*)d_in[2];
  const int* col = (const int*)d_in[3];
  const float* Wq  = (const float*)d_in[4];
  const float* bq  = (const float*)d_in[5];
  const float* Wkv = (const float*)d_in[6];
  const float* bkv = (const float*)d_in[7];
  const float* Wc1 = (const float*)d_in[8];
  const float* Wc2 = (const float*)d_in[9];
  const int N = in_sizes[0] / H;
  const int E = in_sizes[2];
  float* out = (float*)d_out;

  // layout: [qn fp32 | kn fp32]  <-- hn bf16 (N*1024B) aliases exactly
  //         [vn bf16][mlpout][counts|row_start|cursor][eidx][w1f][Wr]
  char* p = (char*)d_ws;
  float* qn = (float*)p;
  float* kn = (float*)(p + (size_t)N*H*4);
  unsigned short* hn = (unsigned short*)p;          // alias qn+kn (dead after alpha)
  p += (size_t)N*H*8;
  unsigned short* vn = (unsigned short*)p;  p += (size_t)N*H*2;
  float* mlpout = (float*)p;                p += (size_t)E*3*4;
  int* counts = (int*)p;                    p += (size_t)N*4;
  int* row_start = (int*)p;                 p += (size_t)(N+1)*4;
  int* cursor = (int*)p;                    p += (size_t)N*4;
  int* eidx = (int*)p;                      p += (size_t)E*4;
  uint4* w1f = (uint4*)((((size_t)p) + 15) & ~(size_t)15);
  float* Wr = (float*)((char*)w1f + 8192*16);

  const size_t need = (size_t)N*H*8 + (size_t)N*H*2 + (size_t)E*3*4
                    + (size_t)N*4*3 + 4 + (size_t)E*4 + 8192*16 + 9*512*4 + 32;
  if (ws_size < need) {
    k_sentinel<<<(out_size + 255)/256, 256, 0, stream>>>(out, out_size);
    return;
  }

  float* hout = out;
  float* cout = out + (size_t)N*H;
  float* aout = cout + (size_t)N*9;   // normalized alpha (edge order)

  k_zero<<<(N + 255)/256, 256, 0, stream>>>((float*)counts, N);
  k_prep_w1<<<32, 256, 0, stream>>>(Wc1, w1f);
  k_prep_wr<<<18, 256, 0, stream>>>(Wkv, Wc1, Wr);
  k_hist<<<(E + 255)/256, 256, 0, stream>>>(row, counts, E);
  k_node_proj<<<(N + 3)/4, 384, 0, stream>>>(h, Wq, bq, Wkv, bkv, qn, kn, vn, N);
  k_scan<<<1, 1024, 0, stream>>>(counts, row_start, cursor, N);
  k_scatter<<<(E + 255)/256, 256, 0, stream>>>(row, cursor, eidx, E);
  k_edge_alpha<<<1024, 256, 0, stream>>>(coord, row, col, Wkv, eidx, qn, kn, aout, E);
  k_row_softmax<<<(N + 255)/256, 256, 0, stream>>>(row_start, eidx, aout, N);
  // qn/kn dead from here: hn overwrites their region
  k_node_hn<<<(N + 127)/128, 256, 0, stream>>>((const unsigned*)vn, w1f, hn, N);
  k_edge_mlp2<<<1024, 256, 0, stream>>>(coord, row, col, Wr, Wc2,
                                        (const uint4*)hn, mlpout, E);
  k_row_final<<<(N + 3)/4, 256, 0, stream>>>(h, coord, col, Wkv, row_start, eidx,
                                             aout, (const unsigned*)vn, mlpout,
                                             hout, cout, N);
}